// Round 2
// baseline (193.289 us; speedup 1.0000x reference)
//
#include <hip/hip_runtime.h>
#include <math.h>

// ---------------- K1: fused input GEMVs (fp32) ----------------
// rows 0..8191 -> mixed, 8192..12287 -> z, 12288..12319 -> b_raw, 12320..12351 -> a_raw
__global__ __launch_bounds__(256) void k_gemv_in(
    const float* __restrict__ x,
    const float* __restrict__ Wqkv,
    const float* __restrict__ Wz,
    const float* __restrict__ Wb,
    const float* __restrict__ Wa,
    float* __restrict__ mixed, float* __restrict__ zb,
    float* __restrict__ b_raw, float* __restrict__ a_raw)
{
  const int tid  = threadIdx.x;
  const int lane = tid & 63;
  const int wave = tid >> 6;

  // x chunk for this lane: 8 x float4 = 32 elements (2048 / 64 lanes)
  float4 xr[8];
  #pragma unroll
  for (int j = 0; j < 8; j++)
    xr[j] = *(const float4*)(x + j*256 + lane*4);

  const int row0 = blockIdx.x * 16 + wave * 4;   // grid 772 -> rows exactly cover 12352
  for (int rr = 0; rr < 4; rr++){
    const int row = row0 + rr;
    const float* W; float* dst;
    if (row < 8192)       { W = Wqkv + (size_t)row * 2048;          dst = mixed + row; }
    else if (row < 12288) { W = Wz   + (size_t)(row-8192) * 2048;   dst = zb + (row-8192); }
    else if (row < 12320) { W = Wb   + (size_t)(row-12288) * 2048;  dst = b_raw + (row-12288); }
    else                  { W = Wa   + (size_t)(row-12320) * 2048;  dst = a_raw + (row-12320); }
    float acc = 0.f;
    #pragma unroll
    for (int j = 0; j < 8; j++){
      float4 w = *(const float4*)(W + j*256 + lane*4);
      acc += w.x*xr[j].x + w.y*xr[j].y + w.z*xr[j].z + w.w*xr[j].w;
    }
    #pragma unroll
    for (int off = 32; off >= 1; off >>= 1) acc += __shfl_xor(acc, off, 64);
    if (lane == 0) *dst = acc;
  }
}

// ---------------- K2: conv + silu + new_conv (fp32) ----------------
__global__ __launch_bounds__(256) void k_conv(
    const float* __restrict__ conv_state,   // 8192 x 3
    const float* __restrict__ conv_w,       // 8192 x 4
    const float* __restrict__ mixed,        // 8192
    float* __restrict__ act,                // 8192 (silu output)
    float* __restrict__ new_conv)           // 8192 x 3
{
  const int c = blockIdx.x * 256 + threadIdx.x;
  const float cs0 = conv_state[c*3+0];
  const float cs1 = conv_state[c*3+1];
  const float cs2 = conv_state[c*3+2];
  const float m   = mixed[c];
  const float w0 = conv_w[c*4+0];
  const float w1 = conv_w[c*4+1];
  const float w2 = conv_w[c*4+2];
  const float w3 = conv_w[c*4+3];
  const float co = cs0*w0 + cs1*w1 + cs2*w2 + m*w3;
  act[c] = co / (1.f + expf(-co));        // silu
  new_conv[c*3+0] = cs1;
  new_conv[c*3+1] = cs2;
  new_conv[c*3+2] = m;
}

// ---------------- K3: per-head state update + gated RMS norm (fp32) ----------------
__global__ __launch_bounds__(128) void k_head(
    const float* __restrict__ act,     // q:0..2047, k:2048..4095, v:4096..8191
    const float* __restrict__ zbuf,    // 4096
    const float* __restrict__ b_raw,   // 32
    const float* __restrict__ a_raw,   // 32
    const float* __restrict__ A_log,   // 32
    const float* __restrict__ dt_bias, // 32
    const float* __restrict__ norm_w,  // 128
    const float* __restrict__ state,   // 32*128*128
    float* __restrict__ new_state,     // 32*128*128
    float* __restrict__ out_flat)      // 4096
{
  const int h = blockIdx.x;
  const int t = threadIdx.x;           // column v index, 0..127
  const int hb = h >> 1;
  const int lane = t & 63, wid = t >> 6;

  __shared__ float qn[128], kn[128];
  __shared__ float red[4];

  const float qv = act[hb*128 + t];
  const float kv = act[2048 + hb*128 + t];
  const float vv = act[4096 + h*128 + t];

  float sq = qv*qv, sk = kv*kv;
  #pragma unroll
  for (int off = 32; off >= 1; off >>= 1){
    sq += __shfl_xor(sq, off, 64);
    sk += __shfl_xor(sk, off, 64);
  }
  if (lane == 0){ red[wid] = sq; red[2+wid] = sk; }
  __syncthreads();
  const float qscale = rsqrtf(red[0]+red[1] + 1e-6f) * 0.088388347648318440550f; // 1/sqrt(128)
  const float kscale = rsqrtf(red[2]+red[3] + 1e-6f);
  qn[t] = qv * qscale;
  kn[t] = kv * kscale;
  __syncthreads();

  float g_t, beta;
  {
    const float av = a_raw[h] + dt_bias[h];
    const float sp = (av > 20.f) ? av : log1pf(expf(av));   // softplus
    g_t  = expf(-expf(A_log[h]) * sp);
    beta = 1.f / (1.f + expf(-b_raw[h]));
  }

  const float* st  = state     + (size_t)h * 16384;
  float*       nst = new_state + (size_t)h * 16384;

  float s[128];
  float kvm = 0.f;
  #pragma unroll
  for (int k = 0; k < 128; k++){
    s[k] = st[k*128 + t] * g_t;
    kvm += s[k] * kn[k];
  }
  const float delta = (vv - kvm) * beta;
  float oacc = 0.f;
  #pragma unroll
  for (int k = 0; k < 128; k++){
    const float ns = s[k] + kn[k] * delta;
    nst[k*128 + t] = ns;
    oacc += ns * qn[k];
  }

  // gated RMS norm
  const float zz = zbuf[h*128 + t];
  const float gated = oacc * (zz / (1.f + expf(-zz)));
  float s2 = gated * gated;
  #pragma unroll
  for (int off = 32; off >= 1; off >>= 1) s2 += __shfl_xor(s2, off, 64);
  if (lane == 0) red[wid] = s2;
  __syncthreads();
  const float mean = (red[0] + red[1]) * (1.f/128.f);
  out_flat[h*128 + t] = gated * rsqrtf(mean + 1e-6f) * norm_w[t];
}

// ---------------- K4: output GEMV (fp32) ----------------
__global__ __launch_bounds__(256) void k_gemv_out(
    const float* __restrict__ out_flat,  // 4096
    const float* __restrict__ Wout,      // 2048 x 4096
    float* __restrict__ out)             // 2048
{
  __shared__ float xs[4096];
  const int tid = threadIdx.x;
  #pragma unroll
  for (int i = 0; i < 16; i++) xs[tid + i*256] = out_flat[tid + i*256];
  __syncthreads();

  const int lane = tid & 63, wave = tid >> 6;
  const int row0 = blockIdx.x * 16 + wave * 4;   // grid 128 -> rows exactly cover 2048
  for (int rr = 0; rr < 4; rr++){
    const int row = row0 + rr;
    const float* W = Wout + (size_t)row * 4096;
    float acc = 0.f;
    #pragma unroll
    for (int j = 0; j < 16; j++){
      float4 w = *(const float4*)(W + j*256 + lane*4);
      acc += w.x*xs[j*256+lane*4+0] + w.y*xs[j*256+lane*4+1]
           + w.z*xs[j*256+lane*4+2] + w.w*xs[j*256+lane*4+3];
    }
    #pragma unroll
    for (int off = 32; off >= 1; off >>= 1) acc += __shfl_xor(acc, off, 64);
    if (lane == 0) out[row] = acc;
  }
}

extern "C" void kernel_launch(void* const* d_in, const int* in_sizes, int n_in,
                              void* d_out, int out_size, void* d_ws, size_t ws_size,
                              hipStream_t stream) {
  const float* x          = (const float*)d_in[0];
  const float* state      = (const float*)d_in[1];
  const float* conv_state = (const float*)d_in[2];
  const float* W_qkv      = (const float*)d_in[3];
  const float* W_z        = (const float*)d_in[4];
  const float* W_b        = (const float*)d_in[5];
  const float* W_a        = (const float*)d_in[6];
  const float* conv_w     = (const float*)d_in[7];
  const float* A_log      = (const float*)d_in[8];
  const float* dt_bias    = (const float*)d_in[9];
  const float* norm_w     = (const float*)d_in[10];
  const float* W_out      = (const float*)d_in[11];

  float* out       = (float*)d_out;                 // 2048
  float* new_state = (float*)d_out + 2048;          // 524288
  float* new_conv  = (float*)d_out + 2048 + 524288; // 24576

  float* ws     = (float*)d_ws;
  float* mixed  = ws;          // 8192
  float* zb     = ws + 8192;   // 4096
  float* b_raw  = ws + 12288;  // 32
  float* a_raw  = ws + 12320;  // 32
  float* act    = ws + 12352;  // 8192
  float* oflat  = ws + 20544;  // 4096

  hipLaunchKernelGGL(k_gemv_in, dim3(772), dim3(256), 0, stream,
                     x, W_qkv, W_z, W_b, W_a, mixed, zb, b_raw, a_raw);
  hipLaunchKernelGGL(k_conv, dim3(32), dim3(256), 0, stream,
                     conv_state, conv_w, mixed, act, new_conv);
  hipLaunchKernelGGL(k_head, dim3(32), dim3(128), 0, stream,
                     act, zb, b_raw, a_raw, A_log, dt_bias, norm_w,
                     state, new_state, oflat);
  hipLaunchKernelGGL(k_gemv_out, dim3(128), dim3(256), 0, stream,
                     oflat, W_out, out);
}

// Round 3
// 180.564 us; speedup vs baseline: 1.0705x; 1.0705x over previous
//
#include <hip/hip_runtime.h>
#include <math.h>

// ---------------- K1: fused input GEMVs (fp32) ----------------
// rows 0..8191 -> mixed, 8192..12287 -> z, 12288..12319 -> b_raw, 12320..12351 -> a_raw
// 2 rows per wave, interleaved loads for MLP. Grid 1544 x 256 thr covers 12352 rows.
__global__ __launch_bounds__(256) void k_gemv_in(
    const float* __restrict__ x,
    const float* __restrict__ Wqkv,
    const float* __restrict__ Wz,
    const float* __restrict__ Wb,
    const float* __restrict__ Wa,
    float* __restrict__ mixed, float* __restrict__ zb,
    float* __restrict__ b_raw, float* __restrict__ a_raw)
{
  const int tid  = threadIdx.x;
  const int lane = tid & 63;
  const int wave = tid >> 6;

  // x chunk for this lane: 8 x float4 = 32 elements (2048 / 64 lanes)
  float4 xr[8];
  #pragma unroll
  for (int j = 0; j < 8; j++)
    xr[j] = *(const float4*)(x + j*256 + lane*4);

  const int row0 = blockIdx.x * 8 + wave * 2;   // even; pair never straddles a segment
  const float* W; float* dst;
  if (row0 < 8192)       { W = Wqkv + (size_t)row0 * 2048;          dst = mixed + row0; }
  else if (row0 < 12288) { W = Wz   + (size_t)(row0-8192) * 2048;   dst = zb + (row0-8192); }
  else if (row0 < 12320) { W = Wb   + (size_t)(row0-12288) * 2048;  dst = b_raw + (row0-12288); }
  else                   { W = Wa   + (size_t)(row0-12320) * 2048;  dst = a_raw + (row0-12320); }

  float acc0 = 0.f, acc1 = 0.f;
  #pragma unroll
  for (int j = 0; j < 8; j++){
    float4 w0 = *(const float4*)(W + j*256 + lane*4);
    float4 w1 = *(const float4*)(W + 2048 + j*256 + lane*4);
    acc0 += w0.x*xr[j].x + w0.y*xr[j].y + w0.z*xr[j].z + w0.w*xr[j].w;
    acc1 += w1.x*xr[j].x + w1.y*xr[j].y + w1.z*xr[j].z + w1.w*xr[j].w;
  }
  #pragma unroll
  for (int off = 32; off >= 1; off >>= 1){
    acc0 += __shfl_xor(acc0, off, 64);
    acc1 += __shfl_xor(acc1, off, 64);
  }
  if (lane == 0){ dst[0] = acc0; dst[1] = acc1; }
}

// ---------------- K2: conv + silu + state update + gated RMS norm ----------------
// One block per head (32 blocks x 128 thr). Each block does conv+SiLU for the
// 3x128 channels it consumes (q/k channels written twice across sibling heads —
// identical values, benign).
__global__ __launch_bounds__(128) void k_head(
    const float* __restrict__ mixed,    // 8192 (pre-conv GEMV output)
    const float* __restrict__ conv_state, // 8192 x 3
    const float* __restrict__ conv_w,     // 8192 x 4
    const float* __restrict__ zbuf,     // 4096
    const float* __restrict__ b_raw,    // 32
    const float* __restrict__ a_raw,    // 32
    const float* __restrict__ A_log,    // 32
    const float* __restrict__ dt_bias,  // 32
    const float* __restrict__ norm_w,   // 128
    const float* __restrict__ state,    // 32*128*128
    float* __restrict__ new_state,      // 32*128*128
    float* __restrict__ new_conv,       // 8192 x 3
    float* __restrict__ out_flat)       // 4096
{
  const int h = blockIdx.x;
  const int t = threadIdx.x;           // column v index, 0..127
  const int hb = h >> 1;
  const int lane = t & 63, wid = t >> 6;

  __shared__ float qn[128], kn[128];
  __shared__ float red[4];

  // conv + silu for q, k, v channels of this head
  const int cq = hb*128 + t;
  const int ck = 2048 + hb*128 + t;
  const int cv = 4096 + h*128 + t;
  float qv, kv, vv;
  {
    float c0, c1, c2, m, w0, w1, w2, w3, co;
    // q
    c0 = conv_state[cq*3+0]; c1 = conv_state[cq*3+1]; c2 = conv_state[cq*3+2];
    m  = mixed[cq];
    w0 = conv_w[cq*4+0]; w1 = conv_w[cq*4+1]; w2 = conv_w[cq*4+2]; w3 = conv_w[cq*4+3];
    co = c0*w0 + c1*w1 + c2*w2 + m*w3;
    qv = co / (1.f + expf(-co));
    new_conv[cq*3+0] = c1; new_conv[cq*3+1] = c2; new_conv[cq*3+2] = m;
    // k
    c0 = conv_state[ck*3+0]; c1 = conv_state[ck*3+1]; c2 = conv_state[ck*3+2];
    m  = mixed[ck];
    w0 = conv_w[ck*4+0]; w1 = conv_w[ck*4+1]; w2 = conv_w[ck*4+2]; w3 = conv_w[ck*4+3];
    co = c0*w0 + c1*w1 + c2*w2 + m*w3;
    kv = co / (1.f + expf(-co));
    new_conv[ck*3+0] = c1; new_conv[ck*3+1] = c2; new_conv[ck*3+2] = m;
    // v
    c0 = conv_state[cv*3+0]; c1 = conv_state[cv*3+1]; c2 = conv_state[cv*3+2];
    m  = mixed[cv];
    w0 = conv_w[cv*4+0]; w1 = conv_w[cv*4+1]; w2 = conv_w[cv*4+2]; w3 = conv_w[cv*4+3];
    co = c0*w0 + c1*w1 + c2*w2 + m*w3;
    vv = co / (1.f + expf(-co));
    new_conv[cv*3+0] = c1; new_conv[cv*3+1] = c2; new_conv[cv*3+2] = m;
  }

  float sq = qv*qv, sk = kv*kv;
  #pragma unroll
  for (int off = 32; off >= 1; off >>= 1){
    sq += __shfl_xor(sq, off, 64);
    sk += __shfl_xor(sk, off, 64);
  }
  if (lane == 0){ red[wid] = sq; red[2+wid] = sk; }
  __syncthreads();
  const float qscale = rsqrtf(red[0]+red[1] + 1e-6f) * 0.088388347648318440550f; // 1/sqrt(128)
  const float kscale = rsqrtf(red[2]+red[3] + 1e-6f);
  qn[t] = qv * qscale;
  kn[t] = kv * kscale;
  __syncthreads();

  float g_t, beta;
  {
    const float av = a_raw[h] + dt_bias[h];
    const float sp = (av > 20.f) ? av : log1pf(expf(av));   // softplus
    g_t  = expf(-expf(A_log[h]) * sp);
    beta = 1.f / (1.f + expf(-b_raw[h]));
  }

  const float* st  = state     + (size_t)h * 16384;
  float*       nst = new_state + (size_t)h * 16384;

  float s[128];
  float kvm = 0.f;
  #pragma unroll
  for (int k = 0; k < 128; k++){
    s[k] = st[k*128 + t] * g_t;
    kvm += s[k] * kn[k];
  }
  const float delta = (vv - kvm) * beta;
  float oacc = 0.f;
  #pragma unroll
  for (int k = 0; k < 128; k++){
    const float ns = s[k] + kn[k] * delta;
    nst[k*128 + t] = ns;
    oacc += ns * qn[k];
  }

  // gated RMS norm
  const float zz = zbuf[h*128 + t];
  const float gated = oacc * (zz / (1.f + expf(-zz)));
  float s2 = gated * gated;
  #pragma unroll
  for (int off = 32; off >= 1; off >>= 1) s2 += __shfl_xor(s2, off, 64);
  if (lane == 0) red[wid] = s2;
  __syncthreads();
  const float mean = (red[0] + red[1]) * (1.f/128.f);
  out_flat[h*128 + t] = gated * rsqrtf(mean + 1e-6f) * norm_w[t];
}

// ---------------- K3: output GEMV (fp32) ----------------
// 256 blocks x 256 thr, 2 rows per wave.
__global__ __launch_bounds__(256) void k_gemv_out(
    const float* __restrict__ out_flat,  // 4096
    const float* __restrict__ Wout,      // 2048 x 4096
    float* __restrict__ out)             // 2048
{
  __shared__ float xs[4096];
  const int tid = threadIdx.x;
  #pragma unroll
  for (int i = 0; i < 4; i++)
    *(float4*)(xs + tid*4 + i*1024) = *(const float4*)(out_flat + tid*4 + i*1024);
  __syncthreads();

  const int lane = tid & 63, wave = tid >> 6;
  const int row0 = blockIdx.x * 8 + wave * 2;   // grid 256 -> rows exactly cover 2048
  const float* W0 = Wout + (size_t)row0 * 4096;
  float acc0 = 0.f, acc1 = 0.f;
  #pragma unroll
  for (int j = 0; j < 16; j++){
    float4 w0 = *(const float4*)(W0 + j*256 + lane*4);
    float4 w1 = *(const float4*)(W0 + 4096 + j*256 + lane*4);
    const float x0 = xs[j*256+lane*4+0], x1 = xs[j*256+lane*4+1];
    const float x2 = xs[j*256+lane*4+2], x3 = xs[j*256+lane*4+3];
    acc0 += w0.x*x0 + w0.y*x1 + w0.z*x2 + w0.w*x3;
    acc1 += w1.x*x0 + w1.y*x1 + w1.z*x2 + w1.w*x3;
  }
  #pragma unroll
  for (int off = 32; off >= 1; off >>= 1){
    acc0 += __shfl_xor(acc0, off, 64);
    acc1 += __shfl_xor(acc1, off, 64);
  }
  if (lane == 0){ out[row0] = acc0; out[row0+1] = acc1; }
}

extern "C" void kernel_launch(void* const* d_in, const int* in_sizes, int n_in,
                              void* d_out, int out_size, void* d_ws, size_t ws_size,
                              hipStream_t stream) {
  const float* x          = (const float*)d_in[0];
  const float* state      = (const float*)d_in[1];
  const float* conv_state = (const float*)d_in[2];
  const float* W_qkv      = (const float*)d_in[3];
  const float* W_z        = (const float*)d_in[4];
  const float* W_b        = (const float*)d_in[5];
  const float* W_a        = (const float*)d_in[6];
  const float* conv_w     = (const float*)d_in[7];
  const float* A_log      = (const float*)d_in[8];
  const float* dt_bias    = (const float*)d_in[9];
  const float* norm_w     = (const float*)d_in[10];
  const float* W_out      = (const float*)d_in[11];

  float* out       = (float*)d_out;                 // 2048
  float* new_state = (float*)d_out + 2048;          // 524288
  float* new_conv  = (float*)d_out + 2048 + 524288; // 24576

  float* ws     = (float*)d_ws;
  float* mixed  = ws;          // 8192
  float* zb     = ws + 8192;   // 4096
  float* b_raw  = ws + 12288;  // 32
  float* a_raw  = ws + 12320;  // 32
  float* oflat  = ws + 12352;  // 4096

  hipLaunchKernelGGL(k_gemv_in, dim3(1544), dim3(256), 0, stream,
                     x, W_qkv, W_z, W_b, W_a, mixed, zb, b_raw, a_raw);
  hipLaunchKernelGGL(k_head, dim3(32), dim3(128), 0, stream,
                     mixed, conv_state, conv_w, zb, b_raw, a_raw, A_log, dt_bias,
                     norm_w, state, new_state, new_conv, oflat);
  hipLaunchKernelGGL(k_gemv_out, dim3(256), dim3(256), 0, stream,
                     oflat, W_out, out);
}

// Round 4
// 177.789 us; speedup vs baseline: 1.0872x; 1.0156x over previous
//
#include <hip/hip_runtime.h>
#include <math.h>

__device__ __forceinline__ float silu(float x){ return x / (1.f + expf(-x)); }

// ---------------- K1: fused input GEMVs (fp32) ----------------
// rows 0..8191 -> mixed, 8192..12287 -> z, 12288..12319 -> b_raw, 12320..12351 -> a_raw
// 2 rows per wave. Grid 1544 x 256 thr covers 12352 rows.
__global__ __launch_bounds__(256) void k_gemv_in(
    const float* __restrict__ x,
    const float* __restrict__ Wqkv,
    const float* __restrict__ Wz,
    const float* __restrict__ Wb,
    const float* __restrict__ Wa,
    float* __restrict__ mixed, float* __restrict__ zb,
    float* __restrict__ b_raw, float* __restrict__ a_raw)
{
  const int tid  = threadIdx.x;
  const int lane = tid & 63;
  const int wave = tid >> 6;

  float4 xr[8];
  #pragma unroll
  for (int j = 0; j < 8; j++)
    xr[j] = *(const float4*)(x + j*256 + lane*4);

  const int row0 = blockIdx.x * 8 + wave * 2;   // even; pair never straddles a segment
  const float* W; float* dst;
  if (row0 < 8192)       { W = Wqkv + (size_t)row0 * 2048;          dst = mixed + row0; }
  else if (row0 < 12288) { W = Wz   + (size_t)(row0-8192) * 2048;   dst = zb + (row0-8192); }
  else if (row0 < 12320) { W = Wb   + (size_t)(row0-12288) * 2048;  dst = b_raw + (row0-12288); }
  else                   { W = Wa   + (size_t)(row0-12320) * 2048;  dst = a_raw + (row0-12320); }

  float acc0 = 0.f, acc1 = 0.f;
  #pragma unroll
  for (int j = 0; j < 8; j++){
    float4 w0 = *(const float4*)(W + j*256 + lane*4);
    float4 w1 = *(const float4*)(W + 2048 + j*256 + lane*4);
    acc0 += w0.x*xr[j].x + w0.y*xr[j].y + w0.z*xr[j].z + w0.w*xr[j].w;
    acc1 += w1.x*xr[j].x + w1.y*xr[j].y + w1.z*xr[j].z + w1.w*xr[j].w;
  }
  #pragma unroll
  for (int off = 32; off >= 1; off >>= 1){
    acc0 += __shfl_xor(acc0, off, 64);
    acc1 += __shfl_xor(acc1, off, 64);
  }
  if (lane == 0){ dst[0] = acc0; dst[1] = acc1; }
}

// ---------------- K2: conv+silu + state update + gated RMSnorm (blocks 0..31)
//                    + W_out L2 prefetch (blocks 32..255) ----------------
// Head blocks: 256 thr, layout cg = tid&31 (4 cols), part = tid>>5 (16 rows).
// Prefetch block p warms W_out rows [p*8, p*8+8) = consumer block p of k_gemv_out
// (same blockIdx -> same XCD under round-robin dispatch).
__global__ __launch_bounds__(256) void k_head(
    const float* __restrict__ mixed,      // 8192 (pre-conv GEMV output)
    const float* __restrict__ conv_state, // 8192 x 3
    const float* __restrict__ conv_w,     // 8192 x 4
    const float* __restrict__ zbuf,       // 4096
    const float* __restrict__ b_raw,      // 32
    const float* __restrict__ a_raw,      // 32
    const float* __restrict__ A_log,      // 32
    const float* __restrict__ dt_bias,    // 32
    const float* __restrict__ norm_w,     // 128
    const float* __restrict__ state,      // 32*128*128
    const float* __restrict__ Wout,       // 2048 x 4096 (prefetch only)
    float* __restrict__ new_state,        // 32*128*128
    float* __restrict__ new_conv,         // 8192 x 3
    float* __restrict__ out_flat,         // 4096
    float* __restrict__ scratch)          // >= 256 floats (prefetch sink)
{
  const int b   = blockIdx.x;
  const int tid = threadIdx.x;

  if (b >= 32){
    // ---- L2 warm for k_gemv_out consumer block b: 8 rows = 8192 float4 ----
    const float4* W4 = (const float4*)Wout + (size_t)b * 8192;
    float4 a = make_float4(0.f, 0.f, 0.f, 0.f);
    #pragma unroll
    for (int j = 0; j < 32; j++){
      float4 w = W4[j*256 + tid];
      a.x += w.x; a.y += w.y; a.z += w.z; a.w += w.w;
    }
    if (tid == 0) scratch[b] = a.x + a.y + a.z + a.w;  // keep loads live
    return;
  }

  const int h  = b;
  const int hb = h >> 1;
  const int t  = tid & 127;
  const int lane = tid & 63, wid = tid >> 6;

  __shared__ float qn[128], kn[128];
  __shared__ __align__(16) float vs[128];
  __shared__ float4 kvp[8][32];
  __shared__ float red[4];

  // ---- conv + silu (threads 0..127: q,k ; threads 128..255: v) ----
  float qv = 0.f, kv = 0.f;
  if (tid < 128){
    int c = hb*128 + t;
    float c0 = conv_state[c*3+0], c1 = conv_state[c*3+1], c2 = conv_state[c*3+2];
    float m  = mixed[c];
    qv = silu(c0*conv_w[c*4+0] + c1*conv_w[c*4+1] + c2*conv_w[c*4+2] + m*conv_w[c*4+3]);
    new_conv[c*3+0] = c1; new_conv[c*3+1] = c2; new_conv[c*3+2] = m;
    c = 2048 + hb*128 + t;
    c0 = conv_state[c*3+0]; c1 = conv_state[c*3+1]; c2 = conv_state[c*3+2];
    m  = mixed[c];
    kv = silu(c0*conv_w[c*4+0] + c1*conv_w[c*4+1] + c2*conv_w[c*4+2] + m*conv_w[c*4+3]);
    new_conv[c*3+0] = c1; new_conv[c*3+1] = c2; new_conv[c*3+2] = m;

    float sq = qv*qv, sk = kv*kv;
    #pragma unroll
    for (int off = 32; off >= 1; off >>= 1){
      sq += __shfl_xor(sq, off, 64);
      sk += __shfl_xor(sk, off, 64);
    }
    if (lane == 0){ red[wid] = sq; red[2+wid] = sk; }
  } else {
    int c = 4096 + h*128 + t;
    float c0 = conv_state[c*3+0], c1 = conv_state[c*3+1], c2 = conv_state[c*3+2];
    float m  = mixed[c];
    vs[t] = silu(c0*conv_w[c*4+0] + c1*conv_w[c*4+1] + c2*conv_w[c*4+2] + m*conv_w[c*4+3]);
    new_conv[c*3+0] = c1; new_conv[c*3+1] = c2; new_conv[c*3+2] = m;
  }
  __syncthreads();
  const float qscale = rsqrtf(red[0]+red[1] + 1e-6f) * 0.088388347648318440550f; // 1/sqrt(128)
  const float kscale = rsqrtf(red[2]+red[3] + 1e-6f);
  if (tid < 128){ qn[t] = qv * qscale; kn[t] = kv * kscale; }
  __syncthreads();

  float g_t, beta;
  {
    const float av = a_raw[h] + dt_bias[h];
    const float sp = (av > 20.f) ? av : log1pf(expf(av));   // softplus
    g_t  = expf(-expf(A_log[h]) * sp);
    beta = 1.f / (1.f + expf(-b_raw[h]));
  }

  // ---- state update: rows k0..k0+15, cols 4*cg..4*cg+3 ----
  const int cg = tid & 31, part = tid >> 5;
  const int k0 = part * 16;
  const float* st  = state     + (size_t)h * 16384;
  float*       nst = new_state + (size_t)h * 16384;

  float4 s4[16];
  float4 kvm = make_float4(0.f, 0.f, 0.f, 0.f);
  #pragma unroll
  for (int i = 0; i < 16; i++){
    float4 sv = *(const float4*)(st + (k0+i)*128 + cg*4);
    sv.x *= g_t; sv.y *= g_t; sv.z *= g_t; sv.w *= g_t;
    s4[i] = sv;
    const float kk = kn[k0+i];
    kvm.x += sv.x*kk; kvm.y += sv.y*kk; kvm.z += sv.z*kk; kvm.w += sv.w*kk;
  }
  kvp[part][cg] = kvm;
  __syncthreads();
  float4 kt = make_float4(0.f, 0.f, 0.f, 0.f);
  #pragma unroll
  for (int p = 0; p < 8; p++){
    float4 kp = kvp[p][cg];
    kt.x += kp.x; kt.y += kp.y; kt.z += kp.z; kt.w += kp.w;
  }
  const float4 v4 = *(const float4*)(vs + cg*4);
  float4 delta;
  delta.x = (v4.x - kt.x) * beta;
  delta.y = (v4.y - kt.y) * beta;
  delta.z = (v4.z - kt.z) * beta;
  delta.w = (v4.w - kt.w) * beta;

  float4 oacc = make_float4(0.f, 0.f, 0.f, 0.f);
  #pragma unroll
  for (int i = 0; i < 16; i++){
    const float kk = kn[k0+i];
    float4 ns;
    ns.x = s4[i].x + kk*delta.x;
    ns.y = s4[i].y + kk*delta.y;
    ns.z = s4[i].z + kk*delta.z;
    ns.w = s4[i].w + kk*delta.w;
    *(float4*)(nst + (k0+i)*128 + cg*4) = ns;
    const float qq = qn[k0+i];
    oacc.x += ns.x*qq; oacc.y += ns.y*qq; oacc.z += ns.z*qq; oacc.w += ns.w*qq;
  }
  __syncthreads();           // kvp reuse
  kvp[part][cg] = oacc;
  __syncthreads();
  if (part == 0){
    float4 o = make_float4(0.f, 0.f, 0.f, 0.f);
    #pragma unroll
    for (int p = 0; p < 8; p++){
      float4 op = kvp[p][cg];
      o.x += op.x; o.y += op.y; o.z += op.z; o.w += op.w;
    }
    const float4 z4 = *(const float4*)(zbuf + h*128 + cg*4);
    float4 g4;
    g4.x = o.x * silu(z4.x);
    g4.y = o.y * silu(z4.y);
    g4.z = o.z * silu(z4.z);
    g4.w = o.w * silu(z4.w);
    float s2 = g4.x*g4.x + g4.y*g4.y + g4.z*g4.z + g4.w*g4.w;
    #pragma unroll
    for (int off = 16; off >= 1; off >>= 1) s2 += __shfl_xor(s2, off, 64);
    const float r = rsqrtf(s2 * (1.f/128.f) + 1e-6f);
    const float4 nw = *(const float4*)(norm_w + cg*4);
    float4 ov;
    ov.x = g4.x * r * nw.x;
    ov.y = g4.y * r * nw.y;
    ov.z = g4.z * r * nw.z;
    ov.w = g4.w * r * nw.w;
    *(float4*)(out_flat + h*128 + cg*4) = ov;
  }
}

// ---------------- K3: output GEMV (fp32), 256 blocks, 2 rows/wave ----------------
__global__ __launch_bounds__(256) void k_gemv_out(
    const float* __restrict__ out_flat,  // 4096
    const float* __restrict__ Wout,      // 2048 x 4096
    float* __restrict__ out)             // 2048
{
  __shared__ float xs[4096];
  const int tid = threadIdx.x;
  #pragma unroll
  for (int i = 0; i < 4; i++)
    *(float4*)(xs + tid*4 + i*1024) = *(const float4*)(out_flat + tid*4 + i*1024);
  __syncthreads();

  const int lane = tid & 63, wave = tid >> 6;
  const int row0 = blockIdx.x * 8 + wave * 2;   // grid 256 -> rows exactly cover 2048
  const float* W0 = Wout + (size_t)row0 * 4096;
  float acc0 = 0.f, acc1 = 0.f;
  #pragma unroll
  for (int j = 0; j < 16; j++){
    float4 w0 = *(const float4*)(W0 + j*256 + lane*4);
    float4 w1 = *(const float4*)(W0 + 4096 + j*256 + lane*4);
    const float x0 = xs[j*256+lane*4+0], x1 = xs[j*256+lane*4+1];
    const float x2 = xs[j*256+lane*4+2], x3 = xs[j*256+lane*4+3];
    acc0 += w0.x*x0 + w0.y*x1 + w0.z*x2 + w0.w*x3;
    acc1 += w1.x*x0 + w1.y*x1 + w1.z*x2 + w1.w*x3;
  }
  #pragma unroll
  for (int off = 32; off >= 1; off >>= 1){
    acc0 += __shfl_xor(acc0, off, 64);
    acc1 += __shfl_xor(acc1, off, 64);
  }
  if (lane == 0){ out[row0] = acc0; out[row0+1] = acc1; }
}

extern "C" void kernel_launch(void* const* d_in, const int* in_sizes, int n_in,
                              void* d_out, int out_size, void* d_ws, size_t ws_size,
                              hipStream_t stream) {
  const float* x          = (const float*)d_in[0];
  const float* state      = (const float*)d_in[1];
  const float* conv_state = (const float*)d_in[2];
  const float* W_qkv      = (const float*)d_in[3];
  const float* W_z        = (const float*)d_in[4];
  const float* W_b        = (const float*)d_in[5];
  const float* W_a        = (const float*)d_in[6];
  const float* conv_w     = (const float*)d_in[7];
  const float* A_log      = (const float*)d_in[8];
  const float* dt_bias    = (const float*)d_in[9];
  const float* norm_w     = (const float*)d_in[10];
  const float* W_out      = (const float*)d_in[11];

  float* out       = (float*)d_out;                 // 2048
  float* new_state = (float*)d_out + 2048;          // 524288
  float* new_conv  = (float*)d_out + 2048 + 524288; // 24576

  float* ws      = (float*)d_ws;
  float* mixed   = ws;          // 8192
  float* zb      = ws + 8192;   // 4096
  float* b_raw   = ws + 12288;  // 32
  float* a_raw   = ws + 12320;  // 32
  float* oflat   = ws + 12352;  // 4096
  float* scratch = ws + 16448;  // 256

  hipLaunchKernelGGL(k_gemv_in, dim3(1544), dim3(256), 0, stream,
                     x, W_qkv, W_z, W_b, W_a, mixed, zb, b_raw, a_raw);
  hipLaunchKernelGGL(k_head, dim3(256), dim3(256), 0, stream,
                     mixed, conv_state, conv_w, zb, b_raw, a_raw, A_log, dt_bias,
                     norm_w, state, W_out, new_state, new_conv, oflat, scratch);
  hipLaunchKernelGGL(k_gemv_out, dim3(256), dim3(256), 0, stream,
                     oflat, W_out, out);
}